// Round 10
// baseline (313.294 us; speedup 1.0000x reference)
//
#include <hip/hip_runtime.h>
#include <hip/hip_bf16.h>
#include <math.h>

#define S_LEN 2048
#define NHEAD 16
#define DHEAD 64
#define DMODEL 1024
#define NBATCH 2

typedef unsigned short u16;
typedef __attribute__((ext_vector_type(8))) short bf16x8;
typedef __attribute__((ext_vector_type(4))) short short4v;
typedef __attribute__((ext_vector_type(4))) float f32x4;

__device__ __forceinline__ short f2bs(float x) {
    __hip_bfloat16 h = __float2bfloat16(x);
    return __builtin_bit_cast(short, h);
}

__device__ __forceinline__ float bs2f(u16 x) {
    __hip_bfloat16 h = __builtin_bit_cast(__hip_bfloat16, (short)x);
    return __bfloat162float(h);
}

#define GL2LDS(g, l)                                                         \
    __builtin_amdgcn_global_load_lds(                                        \
        (const __attribute__((address_space(1))) void*)(g),                  \
        (__attribute__((address_space(3))) void*)(l), 16, 0, 0)

// ---------------------------------------------------------------------------
// prep_all = cast_all + transp_cast_all fused into one dispatch.
// ---------------------------------------------------------------------------
__global__ __launch_bounds__(256) void prep_all(
    const float* __restrict__ x, const float* __restrict__ rpos,
    const float* __restrict__ Wqkv, const float* __restrict__ Wrel,
    const float* __restrict__ Wout,
    u16* __restrict__ xb, u16* __restrict__ rposb,
    u16* __restrict__ Wqkvt, u16* __restrict__ Wrelt, u16* __restrict__ Woutt)
{
    int bid = blockIdx.x;
    if (bid < 6144) {
        const float* in;
        u16* out;
        if (bid < 4096) { in = x; out = xb; }
        else            { in = rpos; out = rposb; bid -= 4096; }
        const int i = (bid * 256 + threadIdx.x) * 4;
        float4 v = *(const float4*)(in + i);
        short4v t;
        t[0] = f2bs(v.x); t[1] = f2bs(v.y); t[2] = f2bs(v.z); t[3] = f2bs(v.w);
        *(short4v*)(out + i) = t;
        return;
    }
    bid -= 6144;                      // 0..1279
    int bx = bid % 80;
    const int ky = bid / 80;          // 0..15
    __shared__ float t[64][65];
    const float* W;
    u16* Wt;
    int N;
    if (bx < 48)      { W = Wqkv; Wt = Wqkvt; N = 3 * DMODEL; }
    else if (bx < 64) { W = Wrel; Wt = Wrelt; N = DMODEL; bx -= 48; }
    else              { W = Wout; Wt = Woutt; N = DMODEL; bx -= 64; }
    const int k0 = ky * 64, n0 = bx * 64;
    const int r = threadIdx.x >> 4;
    const int c4 = (threadIdx.x & 15) * 4;
    #pragma unroll
    for (int it = 0; it < 4; ++it) {
        float4 v = *(const float4*)(W + (size_t)(k0 + it * 16 + r) * N + n0 + c4);
        t[c4 + 0][it * 16 + r] = v.x;
        t[c4 + 1][it * 16 + r] = v.y;
        t[c4 + 2][it * 16 + r] = v.z;
        t[c4 + 3][it * 16 + r] = v.w;
    }
    __syncthreads();
    #pragma unroll
    for (int it = 0; it < 4; ++it) {
        const int nn = it * 16 + r;
        short4v o;
        o[0] = f2bs(t[nn][c4 + 0]); o[1] = f2bs(t[nn][c4 + 1]);
        o[2] = f2bs(t[nn][c4 + 2]); o[3] = f2bs(t[nn][c4 + 3]);
        *(short4v*)(Wt + (size_t)(n0 + nn) * DMODEL + k0 + c4) = o;
    }
}

// ---------------------------------------------------------------------------
// GEMM main-loop macro v5: 128x128 tile, BK=32 (round-9 verified swizzle),
// 3-BUFFER COUNTED-VMCNT pipeline (T4). The old 2-phase used __syncthreads
// whose compiler-emitted vmcnt(0) drained each wave's OWN newest prefetch
// every step (round-9 showed co-resident blocks don't absorb this). Now:
//   prologue: stage(0), stage(1)
//   iter k:   vmcnt(4) [0 on last]  -> stage(k) landed, stage(k+1) in flight
//             s_barrier + sched_barrier(0)  (all waves' stage(k) visible;
//                                            nothing moves across)
//             issue stage(k+2) -> buf[(k+2)%3]  (last read at compute(k-1),
//                                                which is behind the barrier)
//             compute(k) from buf[k%3]
// Each stage's 4 loads get TWO compute phases of flight; no wave ever waits
// on its own latest prefetch. 48KB LDS -> 3 blocks/CU.
// ---------------------------------------------------------------------------
#define GEMM_STAGE32(Aptr, Btptr, Kdim, kk, buf_)                             \
    _Pragma("unroll")                                                         \
    for (int it = 0; it < 2; ++it) {                                          \
        const int c = it * 256 + tid;                                         \
        const int r = c >> 2;                                                 \
        const int o = (((c & 3) ^ (r & 3) ^ ((r >> 2) & 3)) * 8);             \
        GL2LDS((Aptr) + (size_t)(bm + r) * (Kdim) + (kk) + o,                 \
               As[buf_] + (size_t)c * 8);                                     \
        GL2LDS((Btptr) + (size_t)(bn + r) * (Kdim) + (kk) + o,                \
               Bs[buf_] + (size_t)c * 8);                                     \
    }

#define GEMM_BODY_BMN(Aptr, Btptr, Kdim, BM_, BN_)                            \
    __shared__ u16 As[3][128 * 32];                                           \
    __shared__ u16 Bs[3][128 * 32];                                           \
    const int tid = threadIdx.x;                                              \
    const int lane = tid & 63;                                                \
    const int w = tid >> 6;                                                   \
    const int quad = lane >> 4, col = lane & 15;                              \
    const int bm = (BM_), bn = (BN_);                                         \
    const int wm = (w >> 1) * 64, wn = (w & 1) * 64;                          \
    (void)lane;                                                               \
    f32x4 acc[4][4];                                                          \
    _Pragma("unroll")                                                         \
    for (int mt = 0; mt < 4; ++mt)                                            \
        _Pragma("unroll")                                                     \
        for (int nt = 0; nt < 4; ++nt) acc[mt][nt] = (f32x4){0.f,0.f,0.f,0.f};\
    GEMM_STAGE32(Aptr, Btptr, Kdim, 0, 0)                                     \
    GEMM_STAGE32(Aptr, Btptr, Kdim, 32, 1)                                    \
    int kb_ = 0, sb_ = 2;                                                     \
    for (int k0 = 0; k0 < (Kdim); k0 += 32) {                                 \
        if (k0 + 32 < (Kdim)) asm volatile("s_waitcnt vmcnt(4)" ::: "memory");\
        else                  asm volatile("s_waitcnt vmcnt(0)" ::: "memory");\
        __builtin_amdgcn_s_barrier();                                         \
        __builtin_amdgcn_sched_barrier(0);                                    \
        if (k0 + 64 < (Kdim)) { GEMM_STAGE32(Aptr, Btptr, Kdim, k0 + 64, sb_) } \
        bf16x8 af[4], bfr[4];                                                 \
        _Pragma("unroll")                                                     \
        for (int t = 0; t < 4; ++t) {                                         \
            const int am = wm + t * 16 + col;                                 \
            const int aj = quad ^ (am & 3) ^ ((am >> 2) & 3);                 \
            af[t] = *(const bf16x8*)&As[kb_][(size_t)am * 32 + aj * 8];       \
            const int bn2 = wn + t * 16 + col;                                \
            const int bj = quad ^ (bn2 & 3) ^ ((bn2 >> 2) & 3);               \
            bfr[t] = *(const bf16x8*)&Bs[kb_][(size_t)bn2 * 32 + bj * 8];     \
        }                                                                     \
        _Pragma("unroll")                                                     \
        for (int mt = 0; mt < 4; ++mt)                                        \
            _Pragma("unroll")                                                 \
            for (int nt = 0; nt < 4; ++nt)                                    \
                acc[mt][nt] = __builtin_amdgcn_mfma_f32_16x16x32_bf16(        \
                    af[mt], bfr[nt], acc[mt][nt], 0, 0, 0);                   \
        kb_ = (kb_ == 2) ? 0 : kb_ + 1;                                       \
        sb_ = (sb_ == 2) ? 0 : sb_ + 1;                                       \
    }

// ---------------------------------------------------------------------------
// gemm_qkv_rel: qkv GEMM (768) + rel GEMM (128), one dispatch. v5 body,
// round-3 scatter epilogues, XCD-chunked remap (bijective 896%8==0).
// 48KB LDS -> 3 blocks/CU; (256,3) caps VGPR at ~170 (body ~110, no spill).
// ---------------------------------------------------------------------------
__global__ __launch_bounds__(256, 3) void gemm_qkv_rel(
    const u16* __restrict__ A, const u16* __restrict__ Bt,
    const u16* __restrict__ Ar, const u16* __restrict__ Brt,
    const float* __restrict__ rwb, const float* __restrict__ rrb,
    u16* __restrict__ qrw_b, u16* __restrict__ qrr_b,
    u16* __restrict__ kb, u16* __restrict__ vbT,
    u16* __restrict__ rkb)
{
    const int raw = blockIdx.x;
    const int id = (raw & 7) * 112 + (raw >> 3);      // XCD-chunked remap
    const bool isQ = id < 768;
    int bx, by;
    if (isQ) { bx = id % 24; by = id / 24; }          // qkv: (24, 32)
    else     { const int t = id - 768; bx = t % 8; by = t / 8; }  // rel: (8, 16)
    const u16* Ap = isQ ? A  : Ar;
    const u16* Bp = isQ ? Bt : Brt;
    GEMM_BODY_BMN(Ap, Bp, DMODEL, by * 128, bx * 128)
    if (isQ) {
        #pragma unroll
        for (int mt = 0; mt < 4; ++mt) {
            const int row0 = bm + wm + mt * 16 + quad * 4;
            const int b = row0 >> 11;
            const int s0 = row0 & 2047;
            #pragma unroll
            for (int nt = 0; nt < 4; ++nt) {
                const int cn = bn + wn + nt * 16 + col;     // [0,3072)
                const int sec = cn >> 10;                   // wave-uniform per nt
                const int cc = cn & 1023;
                const int h = cc >> 6, d = cc & 63;
                const int bh = b * NHEAD + h;
                if (sec == 0) {
                    const float bw = rwb[cc], br = rrb[cc];
                    #pragma unroll
                    for (int r = 0; r < 4; ++r) {
                        const size_t o = ((size_t)bh * S_LEN + s0 + r) * 64 + d;
                        qrw_b[o] = (u16)f2bs(acc[mt][nt][r] + bw);
                        qrr_b[o] = (u16)f2bs(acc[mt][nt][r] + br);
                    }
                } else if (sec == 1) {
                    #pragma unroll
                    for (int r = 0; r < 4; ++r)
                        kb[((size_t)bh * S_LEN + s0 + r) * 64 + d] =
                            (u16)f2bs(acc[mt][nt][r]);
                } else {
                    short4v t;
                    t[0] = f2bs(acc[mt][nt][0]); t[1] = f2bs(acc[mt][nt][1]);
                    t[2] = f2bs(acc[mt][nt][2]); t[3] = f2bs(acc[mt][nt][3]);
                    *(short4v*)(vbT + ((size_t)bh * 64 + d) * S_LEN + s0) = t;
                }
            }
        }
    } else {
        #pragma unroll
        for (int mt = 0; mt < 4; ++mt) {
            const int l0 = bm + wm + mt * 16 + quad * 4;
            #pragma unroll
            for (int nt = 0; nt < 4; ++nt) {
                const int cn = bn + wn + nt * 16 + col;
                const int h = cn >> 6, d = cn & 63;
                #pragma unroll
                for (int r = 0; r < 4; ++r)
                    rkb[((size_t)h * S_LEN + l0 + r) * 64 + d] =
                        (u16)f2bs(acc[mt][nt][r]);
            }
        }
    }
}

// ---------------------------------------------------------------------------
// gemm_out: 128x64 tile, BK=32, 3-buffer counted-vmcnt (3 loads/stage:
// 2 A + 1 B -> vmcnt(3)/vmcnt(0)), XCD remap. 36KB LDS -> 4 blocks/CU.
// ---------------------------------------------------------------------------
__global__ __launch_bounds__(256, 4) void gemm_out(
    const u16* __restrict__ A, const u16* __restrict__ Bt,
    float* __restrict__ Cf, int N, int K)
{
    __shared__ u16 As[3][128 * 32];
    __shared__ u16 Bs[3][64 * 32];
    const int tid = threadIdx.x;
    const int lane = tid & 63;
    const int w = tid >> 6;
    const int quad = lane >> 4, col = lane & 15;
    const int id0 = blockIdx.x + 16 * blockIdx.y;     // 0..511
    const int wid = (id0 & 7) * 64 + (id0 >> 3);      // XCD-chunked remap
    const int bm = (wid >> 4) * 128, bn = (wid & 15) * 64;
    const int wm = (w >> 1) * 64, wn = (w & 1) * 32;
    f32x4 acc[4][2];
    #pragma unroll
    for (int mt = 0; mt < 4; ++mt)
        #pragma unroll
        for (int nt = 0; nt < 2; ++nt) acc[mt][nt] = (f32x4){0.f,0.f,0.f,0.f};

#define GO_STAGE(kk, buf_)                                                    \
    _Pragma("unroll")                                                         \
    for (int it = 0; it < 2; ++it) {                                          \
        const int c = it * 256 + tid;                                         \
        const int r = c >> 2;                                                 \
        const int o = (((c & 3) ^ (r & 3) ^ ((r >> 2) & 3)) * 8);             \
        GL2LDS(A + (size_t)(bm + r) * K + (kk) + o, As[buf_] + (size_t)c * 8);\
    }                                                                         \
    {                                                                         \
        const int c = tid;                                                    \
        const int r = c >> 2;                                                 \
        const int o = (((c & 3) ^ (r & 3) ^ ((r >> 2) & 3)) * 8);             \
        GL2LDS(Bt + (size_t)(bn + r) * K + (kk) + o, Bs[buf_] + (size_t)c * 8);\
    }

    GO_STAGE(0, 0)
    GO_STAGE(32, 1)
    int kb_ = 0, sb_ = 2;
    for (int k0 = 0; k0 < K; k0 += 32) {
        if (k0 + 32 < K) asm volatile("s_waitcnt vmcnt(3)" ::: "memory");
        else             asm volatile("s_waitcnt vmcnt(0)" ::: "memory");
        __builtin_amdgcn_s_barrier();
        __builtin_amdgcn_sched_barrier(0);
        if (k0 + 64 < K) { GO_STAGE(k0 + 64, sb_) }
        bf16x8 af[4], bfr[2];
        #pragma unroll
        for (int t = 0; t < 4; ++t) {
            const int am = wm + t * 16 + col;
            const int aj = quad ^ (am & 3) ^ ((am >> 2) & 3);
            af[t] = *(const bf16x8*)&As[kb_][(size_t)am * 32 + aj * 8];
        }
        #pragma unroll
        for (int t = 0; t < 2; ++t) {
            const int bn2 = wn + t * 16 + col;
            const int bj = quad ^ (bn2 & 3) ^ ((bn2 >> 2) & 3);
            bfr[t] = *(const bf16x8*)&Bs[kb_][(size_t)bn2 * 32 + bj * 8];
        }
        #pragma unroll
        for (int mt = 0; mt < 4; ++mt)
            #pragma unroll
            for (int nt = 0; nt < 2; ++nt)
                acc[mt][nt] = __builtin_amdgcn_mfma_f32_16x16x32_bf16(
                    af[mt], bfr[nt], acc[mt][nt], 0, 0, 0);
        kb_ = (kb_ == 2) ? 0 : kb_ + 1;
        sb_ = (sb_ == 2) ? 0 : sb_ + 1;
    }
#undef GO_STAGE
    #pragma unroll
    for (int mt = 0; mt < 4; ++mt)
        #pragma unroll
        for (int nt = 0; nt < 2; ++nt)
            #pragma unroll
            for (int r = 0; r < 4; ++r) {
                const int row = bm + wm + mt * 16 + quad * 4 + r;
                const int cn = bn + wn + nt * 16 + col;
                Cf[(size_t)row * N + cn] = acc[mt][nt][r];
            }
}

// ---------------------------------------------------------------------------
// MFMA bf16 flash attention v12 (round-8 VERBATIM): v10 pipeline +
// select-skip + XCD remap (FETCH 141MB -> 20.6MB verified; flash is
// LDS/VALU-structural, not BW-bound).
// ---------------------------------------------------------------------------
__global__ __launch_bounds__(512, 2) void flash_attn(
    const u16* __restrict__ qrw_b, const u16* __restrict__ qrr_b,
    const u16* __restrict__ kb, const u16* __restrict__ vbT,
    const u16* __restrict__ rkb, const int* __restrict__ mask,
    u16* __restrict__ ctxb)
{
    const int lane = threadIdx.x & 63;
    const int w    = threadIdx.x >> 6;      // 0..7
    const int quad = lane >> 4;
    const int col  = lane & 15;
    const int id0  = blockIdx.x + 16 * blockIdx.y;    // 0..511 (x fastest)
    const int wid  = (id0 & 7) * 64 + (id0 >> 3);     // XCD-chunked remap
    const int bh   = wid >> 4;
    const int b    = bh >> 4;
    const int n    = bh & 15;
    const int B0   = (wid & 15) * 128;
    const int iw0  = B0 + w * 16;

    __shared__ u16 Ks[2][64 * 64];   // XOR-swizzled, double-buffered
    __shared__ u16 Vs[2][64 * 64];
    __shared__ u16 Rs[192 * 64];     // rk panel (circular, 3 x 64 rows)
    __shared__ u16 Pr[8][16][72];
    __shared__ u16 maddb[S_LEN];     // bf16 mask-add (0 or -16384)

    const size_t headQ = (size_t)bh * S_LEN * 64;
    const size_t headR = (size_t)n  * S_LEN * 64;

    for (int i = threadIdx.x; i < S_LEN; i += 512)
        maddb[i] = (u16)f2bs(mask[b * S_LEN + i] ? -16384.f : 0.f);

    bf16x8 a_rw[2], a_rr0[2], a_rr1[2];
    {
        const int r0 = iw0 + col;
        const int r1 = (r0 + 1 < S_LEN) ? (r0 + 1) : (S_LEN - 1);
        #pragma unroll
        for (int kc = 0; kc < 2; ++kc) {
            const int doff = kc * 32 + quad * 8;
            a_rw[kc]  = *(const bf16x8*)(qrw_b + headQ + (size_t)r0 * 64 + doff);
            a_rr0[kc] = *(const bf16x8*)(qrr_b + headQ + (size_t)r0 * 64 + doff);
            a_rr1[kc] = *(const bf16x8*)(qrr_b + headQ + (size_t)r1 * 64 + doff);
        }
    }

    f32x4 O[4];
    float l_acc[4] = {0.f, 0.f, 0.f, 0.f};
    #pragma unroll
    for (int dt = 0; dt < 4; ++dt) O[dt] = (f32x4){0.f, 0.f, 0.f, 0.f};

    const int swz  = ((lane & 7) ^ ((lane >> 3) & 7)) * 8;
    const int lrow = lane >> 3;
    const int csel = col & 7;

    // ---- prologue: stage step 0 (K, V chunk w; full 192-row R panel) ----
    {
        const int pbase0 = S_LEN - 128 - B0;        // dblk = B0 >= 0
        GL2LDS(kb + headQ + (size_t)(w * 8 + lrow) * 64 + swz, Ks[0] + w * 512);
        GL2LDS(vbT + ((size_t)bh * 64 + w * 8 + lrow) * S_LEN + swz, Vs[0] + w * 512);
        #pragma unroll
        for (int t = 0; t < 3; ++t) {
            const int c = w * 3 + t;                // 0..23
            int rr = pbase0 + c * 8 + lrow;
            rr = rr < 0 ? 0 : (rr > S_LEN - 1 ? S_LEN - 1 : rr);
            GL2LDS(rkb + headR + (size_t)rr * 64 + swz, Rs + c * 512);
        }
    }
    int roff = 0;
    __syncthreads();    // drains prologue vmcnt

    for (int u0 = 0; u0 < S_LEN; u0 += 64) {
        const int dblk = B0 - u0;                 // block-uniform, mult of 64
        const int dw = dblk + 16 * w;             // wave-uniform
        const bool mixed = (dw >= 0) && (dw <= 48);
        const int buf = (u0 >> 6) & 1;
        const int u1 = u0 + 64;
        const bool have_next = u1 < S_LEN;
        const bool next_full = (B0 - u1) == -64;  // region boundary ahead

        // mixed waves: direct-VGPR loads of the other region (issued FIRST so
        // their counted vmcnt wait doesn't drain the prefetches below)
        bf16x8 rf2[5][2];
        if (mixed) {
            #pragma unroll
            for (int g = 0; g < 5; ++g) {
                const int u = g * 16 + col;
                int row = (dblk >= 0) ? (u - dw - 17) : (S_LEN - 16 - dw + u);
                row = row < 0 ? 0 : (row > S_LEN - 1 ? S_LEN - 1 : row);
                const u16* rb = rkb + headR + (size_t)row * 64 + quad * 8;
                rf2[g][0] = *(const bf16x8*)(rb);
                rf2[g][1] = *(const bf16x8*)(rb + 32);
            }
        }

        // ---- prefetch next step: K/V -> alt LDS buffer, rk rows -> regs ----
        bf16x8 rpre;
        if (have_next) {
            GL2LDS(kb + headQ + (size_t)(u1 + w * 8 + lrow) * 64 + swz,
                   Ks[buf ^ 1] + w * 512);
            GL2LDS(vbT + ((size_t)bh * 64 + w * 8 + lrow) * S_LEN + u1 + swz,
                   Vs[buf ^ 1] + w * 512);
            if (!next_full) {
                const int dn = B0 - u1;
                const int pb = (dn >= 0) ? (S_LEN - 128 - dn) : (-dn - 129);
                int rr = pb + 128 + w * 8 + lrow;
                rr = rr < 0 ? 0 : (rr > S_LEN - 1 ? S_LEN - 1 : rr);
                rpre = *(const bf16x8*)(rkb + headR + (size_t)rr * 64 + swz);
            }
        }

        // ---- ac = Qrw . K^T ----
        f32x4 sc[4];
        #pragma unroll
        for (int nt = 0; nt < 4; ++nt) {
            const int m = nt * 16 + col;
            bf16x8 k0 = *(const bf16x8*)&Ks[buf][m * 64 + ((quad ^ csel) * 8)];
            bf16x8 k1 = *(const bf16x8*)&Ks[buf][m * 64 + (((4 + quad) ^ csel) * 8)];
            f32x4 c = (f32x4){0.f, 0.f, 0.f, 0.f};
            c = __builtin_amdgcn_mfma_f32_16x16x32_bf16(a_rw[0], k0, c, 0, 0, 0);
            c = __builtin_amdgcn_mfma_f32_16x16x32_bf16(a_rw[1], k1, c, 0, 0, 0);
            sc[nt] = c;
        }

        // ---- bd: panel GEMM ----
        f32x4 pnl[5];
        {
            const bf16x8* aP = (dblk >= 0) ? a_rr0 : a_rr1;
            #pragma unroll
            for (int g = 0; g < 5; ++g) {
                const int m = g * 16 + col + 112 - 16 * w;   // m&7 == col&7
                int slot = m + roff; if (slot >= 192) slot -= 192;
                bf16x8 r0 = *(const bf16x8*)&Rs[slot * 64 + ((quad ^ csel) * 8)];
                bf16x8 r1 = *(const bf16x8*)&Rs[slot * 64 + (((4 + quad) ^ csel) * 8)];
                f32x4 c = (f32x4){0.f, 0.f, 0.f, 0.f};
                c = __builtin_amdgcn_mfma_f32_16x16x32_bf16(aP[0], r0, c, 0, 0, 0);
                c = __builtin_amdgcn_mfma_f32_16x16x32_bf16(aP[1], r1, c, 0, 0, 0);
                pnl[g] = c;
            }
        }
        // ---- region stitch: only mixed waves and the dw==-16 wave differ
        //      from identity; wave-uniform branch. ----
        if (mixed || dw == -16) {
            f32x4 oth[5];
            #pragma unroll
            for (int g = 0; g < 5; ++g) oth[g] = (f32x4){0.f, 0.f, 0.f, 0.f};
            if (mixed) {
                const bf16x8* aV = (dblk >= 0) ? a_rr1 : a_rr0;
                #pragma unroll
                for (int g = 0; g < 5; ++g) {
                    f32x4 c = (f32x4){0.f, 0.f, 0.f, 0.f};
                    c = __builtin_amdgcn_mfma_f32_16x16x32_bf16(aV[0], rf2[g][0], c, 0, 0, 0);
                    c = __builtin_amdgcn_mfma_f32_16x16x32_bf16(aV[1], rf2[g][1], c, 0, 0, 0);
                    oth[g] = c;
                }
            }
            const int lim1 = 15 + dw;
            #pragma unroll
            for (int g = 0; g < 5; ++g) {
                const int u = g * 16 + col;
                #pragma unroll
                for (int r = 0; r < 4; ++r) {
                    const float r1v = (dblk >= 0) ? pnl[g][r] : oth[g][r];
                    const float r2v = (dblk >= 0) ? oth[g][r] : pnl[g][r];
                    pnl[g][r] = (u <= lim1) ? r1v : ((u == lim1 + 1) ? 0.f : r2v);
                }
            }
        }

        // ---- extract diagonal, add ac, scale, mask, exp, accumulate l ----
        #pragma unroll
        for (int nt = 0; nt < 4; ++nt) {
            const float ma = bs2f(maddb[u0 + nt * 16 + col]);
            #pragma unroll
            for (int r = 0; r < 4; ++r) {
                const int uo = col + 15 - quad * 4 - r;      // [0,30]
                const int src = (quad << 4) | (uo & 15);
                float blo = __shfl(pnl[nt][r], src, 64);
                float bhi = __shfl(pnl[nt + 1][r], src, 64);
                float bd = (uo < 16) ? blo : bhi;
                float p = __expf(fmaf(sc[nt][r] + bd, 0.125f, ma));
                sc[nt][r] = p;
                l_acc[r] += p;
            }
        }

        // ---- P: C-layout -> LDS row-major -> A-frags ----
        #pragma unroll
        for (int nt = 0; nt < 4; ++nt)
            #pragma unroll
            for (int r = 0; r < 4; ++r)
                Pr[w][quad * 4 + r][nt * 16 + col] = (u16)f2bs(sc[nt][r]);
        bf16x8 pa[2];
        pa[0] = *(const bf16x8*)&Pr[w][col][quad * 8];
        pa[1] = *(const bf16x8*)&Pr[w][col][32 + quad * 8];

        // ---- O += P . V ----
        #pragma unroll
        for (int dt = 0; dt < 4; ++dt) {
            const int m = dt * 16 + col;
            bf16x8 v0 = *(const bf16x8*)&Vs[buf][m * 64 + ((quad ^ csel) * 8)];
            bf16x8 v1 = *(const bf16x8*)&Vs[buf][m * 64 + (((4 + quad) ^ csel) * 8)];
            f32x4 c = O[dt];
            c = __builtin_amdgcn_mfma_f32_16x16x32_bf16(pa[0], v0, c, 0, 0, 0);
            c = __builtin_amdgcn_mfma_f32_16x16x32_bf16(pa[1], v1, c, 0, 0, 0);
            O[dt] = c;
        }

        // ---- publish next step's staging ----
        if (have_next) {
            __syncthreads();    // end of compute; K/V prefetch drains here (free)
            if (next_full) {
                // full R restage for the new region (pbase = -65), 3 chunks/wave
                #pragma unroll
                for (int t = 0; t < 3; ++t) {
                    const int c = w * 3 + t;
                    int rr = -65 + c * 8 + lrow;
                    rr = rr < 0 ? 0 : (rr > S_LEN - 1 ? S_LEN - 1 : rr);
                    GL2LDS(rkb + headR + (size_t)rr * 64 + swz, Rs + c * 512);
                }
                roff = 0;
            } else {
                // rolling: write the 8 prefetched rows into slots [roff, roff+64)
                *(bf16x8*)&Rs[((size_t)(roff + w * 8) << 6) + lane * 8] = rpre;
                roff += 64; if (roff >= 192) roff -= 192;
            }
            __syncthreads();    // publish Rs writes / drain boundary restage
        }
    }

    float inv[4];
    #pragma unroll
    for (int r = 0; r < 4; ++r) {
        float s = l_acc[r];
        #pragma unroll
        for (int off = 1; off < 16; off <<= 1)
            s += __shfl_xor(s, off, 64);
        inv[r] = 1.f / s;
    }
    #pragma unroll
    for (int dt = 0; dt < 4; ++dt)
        #pragma unroll
        for (int r = 0; r < 4; ++r) {
            const int i = iw0 + quad * 4 + r;
            ctxb[((size_t)b * S_LEN + i) * DMODEL + n * 64 + dt * 16 + col] =
                (u16)f2bs(O[dt][r] * inv[r]);
        }
}

// ---------------------------------------------------------------------------
// out = LayerNorm(x + attn_out)
// ---------------------------------------------------------------------------
__global__ __launch_bounds__(256) void ln_kernel(const float* __restrict__ x,
                                                 const float* __restrict__ ao,
                                                 const float* __restrict__ gamma,
                                                 const float* __restrict__ beta,
                                                 float* __restrict__ out) {
    const int r = blockIdx.x;
    const int tid = threadIdx.x;
    const size_t base = (size_t)r * DMODEL + tid * 4;
    float4 xv = *(const float4*)(x + base);
    float4 av = *(const float4*)(ao + base);
    float v0 = xv.x + av.x, v1 = xv.y + av.y, v2 = xv.z + av.z, v3 = xv.w + av.w;

    float s = v0 + v1 + v2 + v3;
    #pragma unroll
    for (int off = 32; off > 0; off >>= 1) s += __shfl_xor(s, off, 64);
    __shared__ float red[4];
    __shared__ float red2[4];
    if ((tid & 63) == 0) red[tid >> 6] = s;
    __syncthreads();
    float mu = (red[0] + red[1] + red[2] + red[3]) * (1.0f / DMODEL);

    float d0 = v0 - mu, d1 = v1 - mu, d2 = v2 - mu, d3 = v3 - mu;
    float q = d0 * d0 + d1 * d1 + d2 * d2 + d3 * d3;
    #pragma unroll
    for (int off = 32; off > 0; off >>= 1) q += __shfl_xor(q, off, 64);
    if ((tid & 63) == 0) red2[tid >> 6] = q;
    __syncthreads();
    float var = (red2[0] + red2[1] + red2[2] + red2[3]) * (1.0f / DMODEL);
    float rstd = rsqrtf(var + 1e-5f);

    float4 g  = *(const float4*)(gamma + tid * 4);
    float4 be = *(const float4*)(beta + tid * 4);
    float4 o = make_float4(d0 * rstd * g.x + be.x,
                           d1 * rstd * g.y + be.y,
                           d2 * rstd * g.z + be.z,
                           d3 * rstd * g.w + be.w);
    *(float4*)(out + base) = o;
}

// ---------------------------------------------------------------------------
extern "C" void kernel_launch(void* const* d_in, const int* in_sizes, int n_in,
                              void* d_out, int out_size, void* d_ws, size_t ws_size,
                              hipStream_t stream) {
    const float* x    = (const float*)d_in[0];
    const float* rpos = (const float*)d_in[1];
    const float* rwb  = (const float*)d_in[2];
    const float* rrb  = (const float*)d_in[3];
    const int*   mask = (const int*)  d_in[4];
    const float* Wqkv = (const float*)d_in[5];
    const float* Wrel = (const float*)d_in[6];
    const float* Wout = (const float*)d_in[7];
    const float* gam  = (const float*)d_in[8];
    const float* bet  = (const float*)d_in[9];
    float* out = (float*)d_out;

    // ---- workspace layout (u16 units), ~86 MB ----
    u16* wsb   = (u16*)d_ws;
    u16* ctxb  = wsb;                        // [4096][1024] bf16
    float* ao  = (float*)(wsb + 4194304);    // [4096][1024] f32
    u16* qrw_b = wsb + 12582912;             // [BH][S][64]
    u16* qrr_b = qrw_b + 4194304;
    u16* kb    = qrr_b + 4194304;
    u16* vbT   = kb + 4194304;               // [BH][64][S]
    u16* rkb   = vbT + 4194304;              // [NHEAD][S][64]
    u16* xb    = rkb + 2097152;              // [4096][1024]
    u16* rposb = xb + 4194304;               // [2048][1024]
    u16* Wqkvt = rposb + 2097152;            // [3072][1024]
    u16* Wrelt = Wqkvt + 3145728;            // [1024][1024]
    u16* Woutt = Wrelt + 1048576;            // [1024][1024]

    dim3 blk(256);
    prep_all<<<dim3(7424), blk, 0, stream>>>(x, rpos, Wqkv, Wrel, Wout,
                                             xb, rposb, Wqkvt, Wrelt, Woutt);
    gemm_qkv_rel<<<dim3(896), blk, 0, stream>>>(xb, Wqkvt, rposb, Wrelt,
                                                rwb, rrb,
                                                qrw_b, qrr_b, kb, vbT, rkb);
    flash_attn<<<dim3(S_LEN / 128, NBATCH * NHEAD), dim3(512), 0, stream>>>(
        qrw_b, qrr_b, kb, vbT, rkb, mask, ctxb);
    gemm_out<<<dim3(16, 32), blk, 0, stream>>>(ctxb, Woutt, ao, DMODEL, DMODEL);
    ln_kernel<<<dim3(NBATCH * S_LEN), blk, 0, stream>>>(x, ao, gam, bet, out);
}

// Round 11
// 300.128 us; speedup vs baseline: 1.0439x; 1.0439x over previous
//
#include <hip/hip_runtime.h>
#include <hip/hip_bf16.h>
#include <math.h>

#define S_LEN 2048
#define NHEAD 16
#define DHEAD 64
#define DMODEL 1024
#define NBATCH 2

typedef unsigned short u16;
typedef __attribute__((ext_vector_type(8))) short bf16x8;
typedef __attribute__((ext_vector_type(4))) short short4v;
typedef __attribute__((ext_vector_type(4))) float f32x4;

__device__ __forceinline__ short f2bs(float x) {
    __hip_bfloat16 h = __float2bfloat16(x);
    return __builtin_bit_cast(short, h);
}

__device__ __forceinline__ float bs2f(u16 x) {
    __hip_bfloat16 h = __builtin_bit_cast(__hip_bfloat16, (short)x);
    return __bfloat162float(h);
}

#define GL2LDS(g, l)                                                         \
    __builtin_amdgcn_global_load_lds(                                        \
        (const __attribute__((address_space(1))) void*)(g),                  \
        (__attribute__((address_space(3))) void*)(l), 16, 0, 0)

// ---------------------------------------------------------------------------
// prep_all = cast_all + transp_cast_all fused into one dispatch.
//   bid < 4096  : x cast          (fp32->bf16, 1024 elems/block)
//   bid < 6144  : rpos cast
//   else        : W transpose-cast (80 x 16 tiles flattened)
// ---------------------------------------------------------------------------
__global__ __launch_bounds__(256) void prep_all(
    const float* __restrict__ x, const float* __restrict__ rpos,
    const float* __restrict__ Wqkv, const float* __restrict__ Wrel,
    const float* __restrict__ Wout,
    u16* __restrict__ xb, u16* __restrict__ rposb,
    u16* __restrict__ Wqkvt, u16* __restrict__ Wrelt, u16* __restrict__ Woutt)
{
    int bid = blockIdx.x;
    if (bid < 6144) {
        const float* in;
        u16* out;
        if (bid < 4096) { in = x; out = xb; }
        else            { in = rpos; out = rposb; bid -= 4096; }
        const int i = (bid * 256 + threadIdx.x) * 4;
        float4 v = *(const float4*)(in + i);
        short4v t;
        t[0] = f2bs(v.x); t[1] = f2bs(v.y); t[2] = f2bs(v.z); t[3] = f2bs(v.w);
        *(short4v*)(out + i) = t;
        return;
    }
    bid -= 6144;                      // 0..1279
    int bx = bid % 80;
    const int ky = bid / 80;          // 0..15
    __shared__ float t[64][65];
    const float* W;
    u16* Wt;
    int N;
    if (bx < 48)      { W = Wqkv; Wt = Wqkvt; N = 3 * DMODEL; }
    else if (bx < 64) { W = Wrel; Wt = Wrelt; N = DMODEL; bx -= 48; }
    else              { W = Wout; Wt = Woutt; N = DMODEL; bx -= 64; }
    const int k0 = ky * 64, n0 = bx * 64;
    const int r = threadIdx.x >> 4;
    const int c4 = (threadIdx.x & 15) * 4;
    #pragma unroll
    for (int it = 0; it < 4; ++it) {
        float4 v = *(const float4*)(W + (size_t)(k0 + it * 16 + r) * N + n0 + c4);
        t[c4 + 0][it * 16 + r] = v.x;
        t[c4 + 1][it * 16 + r] = v.y;
        t[c4 + 2][it * 16 + r] = v.z;
        t[c4 + 3][it * 16 + r] = v.w;
    }
    __syncthreads();
    #pragma unroll
    for (int it = 0; it < 4; ++it) {
        const int nn = it * 16 + r;
        short4v o;
        o[0] = f2bs(t[nn][c4 + 0]); o[1] = f2bs(t[nn][c4 + 1]);
        o[2] = f2bs(t[nn][c4 + 2]); o[3] = f2bs(t[nn][c4 + 3]);
        *(short4v*)(Wt + (size_t)(n0 + nn) * DMODEL + k0 + c4) = o;
    }
}

// ---------------------------------------------------------------------------
// GEMM main-loop macro (round-5 v2, verified champion): 128x128 tile, BK=64,
// XOR-swizzled LDS, gl2lds width-16, 2-phase dbuf pipeline (stage k+1 at top
// of compute k, ONE barrier per step). 64KB LDS -> 2 blocks/CU.
// (Verified bounds of this family: BM=64 regressed (r6); BK=32@4blk null
// (r9); 3-buffer counted-vmcnt regressed (r10, m196's coarse-split effect).)
// ---------------------------------------------------------------------------
#define GEMM_BODY_BMN(Aptr, Btptr, Kdim, BM_, BN_)                            \
    __shared__ u16 As[2][128 * 64];                                           \
    __shared__ u16 Bs[2][128 * 64];                                           \
    const int tid = threadIdx.x;                                              \
    const int lane = tid & 63;                                                \
    const int w = tid >> 6;                                                   \
    const int quad = lane >> 4, col = lane & 15;                              \
    const int bm = (BM_), bn = (BN_);                                         \
    const int wm = (w >> 1) * 64, wn = (w & 1) * 64;                          \
    f32x4 acc[4][4];                                                          \
    _Pragma("unroll")                                                         \
    for (int mt = 0; mt < 4; ++mt)                                            \
        _Pragma("unroll")                                                     \
        for (int nt = 0; nt < 4; ++nt) acc[mt][nt] = (f32x4){0.f,0.f,0.f,0.f};\
    _Pragma("unroll")                                                         \
    for (int it = 0; it < 4; ++it) {                                          \
        const int cb = it * 256 + w * 64;                                     \
        const int c = cb + lane;                                              \
        const int r = c >> 3;                                                 \
        const int o = ((c & 7) ^ (r & 7)) * 8;                                \
        GL2LDS((Aptr) + (size_t)(bm + r) * (Kdim) + o, As[0] + (size_t)cb * 8); \
        GL2LDS((Btptr) + (size_t)(bn + r) * (Kdim) + o, Bs[0] + (size_t)cb * 8);\
    }                                                                         \
    __syncthreads();                                                          \
    for (int k0 = 0; k0 < (Kdim); k0 += 64) {                                 \
        const int kbuf = (k0 >> 6) & 1;                                       \
        if (k0 + 64 < (Kdim)) {                                               \
            _Pragma("unroll")                                                 \
            for (int it = 0; it < 4; ++it) {                                  \
                const int cb = it * 256 + w * 64;                             \
                const int c = cb + lane;                                      \
                const int r = c >> 3;                                         \
                const int o = ((c & 7) ^ (r & 7)) * 8;                        \
                GL2LDS((Aptr) + (size_t)(bm + r) * (Kdim) + k0 + 64 + o,      \
                       As[kbuf ^ 1] + (size_t)cb * 8);                        \
                GL2LDS((Btptr) + (size_t)(bn + r) * (Kdim) + k0 + 64 + o,     \
                       Bs[kbuf ^ 1] + (size_t)cb * 8);                        \
            }                                                                 \
        }                                                                     \
        _Pragma("unroll")                                                     \
        for (int kc = 0; kc < 2; ++kc) {                                      \
            bf16x8 af[4], bfr[4];                                             \
            _Pragma("unroll")                                                 \
            for (int t = 0; t < 4; ++t) {                                     \
                const int am = wm + t * 16 + col;                             \
                const int aj = kc * 4 + quad;                                 \
                af[t] = *(const bf16x8*)&As[kbuf][(size_t)am * 64 + ((aj ^ (am & 7)) * 8)]; \
                const int bn2 = wn + t * 16 + col;                            \
                bfr[t] = *(const bf16x8*)&Bs[kbuf][(size_t)bn2 * 64 + ((aj ^ (bn2 & 7)) * 8)]; \
            }                                                                 \
            _Pragma("unroll")                                                 \
            for (int mt = 0; mt < 4; ++mt)                                    \
                _Pragma("unroll")                                             \
                for (int nt = 0; nt < 4; ++nt)                                \
                    acc[mt][nt] = __builtin_amdgcn_mfma_f32_16x16x32_bf16(    \
                        af[mt], bfr[nt], acc[mt][nt], 0, 0, 0);               \
        }                                                                     \
        __syncthreads();                                                      \
    }

// ---------------------------------------------------------------------------
// gemm_qkv_rel: qkv GEMM (768 blocks) + rel GEMM (128 blocks), one dispatch.
// Round-5 exact (v2 body, round-3 scatter epilogues).
// ---------------------------------------------------------------------------
__global__ __launch_bounds__(256, 2) void gemm_qkv_rel(
    const u16* __restrict__ A, const u16* __restrict__ Bt,
    const u16* __restrict__ Ar, const u16* __restrict__ Brt,
    const float* __restrict__ rwb, const float* __restrict__ rrb,
    u16* __restrict__ qrw_b, u16* __restrict__ qrr_b,
    u16* __restrict__ kb, u16* __restrict__ vbT,
    u16* __restrict__ rkb)
{
    const int id = blockIdx.x;
    const bool isQ = id < 768;
    int bx, by;
    if (isQ) { bx = id % 24; by = id / 24; }          // qkv: (24, 32)
    else     { const int t = id - 768; bx = t % 8; by = t / 8; }  // rel: (8, 16)
    const u16* Ap = isQ ? A  : Ar;
    const u16* Bp = isQ ? Bt : Brt;
    GEMM_BODY_BMN(Ap, Bp, DMODEL, by * 128, bx * 128)
    if (isQ) {
        #pragma unroll
        for (int mt = 0; mt < 4; ++mt) {
            const int row0 = bm + wm + mt * 16 + quad * 4;
            const int b = row0 >> 11;
            const int s0 = row0 & 2047;
            #pragma unroll
            for (int nt = 0; nt < 4; ++nt) {
                const int cn = bn + wn + nt * 16 + col;     // [0,3072)
                const int sec = cn >> 10;                   // wave-uniform per nt
                const int cc = cn & 1023;
                const int h = cc >> 6, d = cc & 63;
                const int bh = b * NHEAD + h;
                if (sec == 0) {
                    const float bw = rwb[cc], br = rrb[cc];
                    #pragma unroll
                    for (int r = 0; r < 4; ++r) {
                        const size_t o = ((size_t)bh * S_LEN + s0 + r) * 64 + d;
                        qrw_b[o] = (u16)f2bs(acc[mt][nt][r] + bw);
                        qrr_b[o] = (u16)f2bs(acc[mt][nt][r] + br);
                    }
                } else if (sec == 1) {
                    #pragma unroll
                    for (int r = 0; r < 4; ++r)
                        kb[((size_t)bh * S_LEN + s0 + r) * 64 + d] =
                            (u16)f2bs(acc[mt][nt][r]);
                } else {
                    short4v t;
                    t[0] = f2bs(acc[mt][nt][0]); t[1] = f2bs(acc[mt][nt][1]);
                    t[2] = f2bs(acc[mt][nt][2]); t[3] = f2bs(acc[mt][nt][3]);
                    *(short4v*)(vbT + ((size_t)bh * 64 + d) * S_LEN + s0) = t;
                }
            }
        }
    } else {
        #pragma unroll
        for (int mt = 0; mt < 4; ++mt) {
            const int l0 = bm + wm + mt * 16 + quad * 4;
            #pragma unroll
            for (int nt = 0; nt < 4; ++nt) {
                const int cn = bn + wn + nt * 16 + col;
                const int h = cn >> 6, d = cn & 63;
                #pragma unroll
                for (int r = 0; r < 4; ++r)
                    rkb[((size_t)h * S_LEN + l0 + r) * 64 + d] =
                        (u16)f2bs(acc[mt][nt][r]);
            }
        }
    }
}

// ---------------------------------------------------------------------------
// gemm_out: C = A @ Bt^T, fp32 out. DEDICATED 128x64 tile: at 128x128 the
// grid was 256 blocks = exactly 1 block/CU, so the 2-phase pipeline's
// per-step vmcnt drain had ZERO co-resident cover. 128x64 -> 48KB LDS ->
// 3 blocks/CU, grid 512 -> 2-3 resident: drains hidden. Extra B traffic is
// free (Wout = 2MB, L2-resident). Same verified swizzle (rows still 64 elems).
// ---------------------------------------------------------------------------
__global__ __launch_bounds__(256, 3) void gemm_out(
    const u16* __restrict__ A, const u16* __restrict__ Bt,
    float* __restrict__ Cf, int N, int K)
{
    __shared__ u16 As[2][128 * 64];
    __shared__ u16 Bs[2][64 * 64];
    const int tid = threadIdx.x;
    const int lane = tid & 63;
    const int w = tid >> 6;
    const int quad = lane >> 4, col = lane & 15;
    const int bm = blockIdx.y * 128, bn = blockIdx.x * 64;
    const int wm = (w >> 1) * 64, wn = (w & 1) * 32;
    f32x4 acc[4][2];
    #pragma unroll
    for (int mt = 0; mt < 4; ++mt)
        #pragma unroll
        for (int nt = 0; nt < 2; ++nt) acc[mt][nt] = (f32x4){0.f,0.f,0.f,0.f};

    // prologue stage (k=0) into buf 0: A 4 passes (128 rows), B 2 passes (64)
    #pragma unroll
    for (int it = 0; it < 4; ++it) {
        const int c = it * 256 + tid;
        const int r = c >> 3;
        const int o = ((c & 7) ^ (r & 7)) * 8;
        GL2LDS(A + (size_t)(bm + r) * K + o, As[0] + (size_t)c * 8);
    }
    #pragma unroll
    for (int it = 0; it < 2; ++it) {
        const int c = it * 256 + tid;
        const int r = c >> 3;
        const int o = ((c & 7) ^ (r & 7)) * 8;
        GL2LDS(Bt + (size_t)(bn + r) * K + o, Bs[0] + (size_t)c * 8);
    }
    __syncthreads();
    for (int k0 = 0; k0 < K; k0 += 64) {
        const int kbuf = (k0 >> 6) & 1;
        if (k0 + 64 < K) {
            #pragma unroll
            for (int it = 0; it < 4; ++it) {
                const int c = it * 256 + tid;
                const int r = c >> 3;
                const int o = ((c & 7) ^ (r & 7)) * 8;
                GL2LDS(A + (size_t)(bm + r) * K + k0 + 64 + o,
                       As[kbuf ^ 1] + (size_t)c * 8);
            }
            #pragma unroll
            for (int it = 0; it < 2; ++it) {
                const int c = it * 256 + tid;
                const int r = c >> 3;
                const int o = ((c & 7) ^ (r & 7)) * 8;
                GL2LDS(Bt + (size_t)(bn + r) * K + k0 + 64 + o,
                       Bs[kbuf ^ 1] + (size_t)c * 8);
            }
        }
        #pragma unroll
        for (int kc = 0; kc < 2; ++kc) {
            bf16x8 af[4], bfr[2];
            #pragma unroll
            for (int t = 0; t < 4; ++t) {
                const int am = wm + t * 16 + col;
                const int aj = kc * 4 + quad;
                af[t] = *(const bf16x8*)&As[kbuf][(size_t)am * 64 + ((aj ^ (am & 7)) * 8)];
            }
            #pragma unroll
            for (int t = 0; t < 2; ++t) {
                const int bn2 = wn + t * 16 + col;
                const int aj = kc * 4 + quad;
                bfr[t] = *(const bf16x8*)&Bs[kbuf][(size_t)bn2 * 64 + ((aj ^ (bn2 & 7)) * 8)];
            }
            #pragma unroll
            for (int mt = 0; mt < 4; ++mt)
                #pragma unroll
                for (int nt = 0; nt < 2; ++nt)
                    acc[mt][nt] = __builtin_amdgcn_mfma_f32_16x16x32_bf16(
                        af[mt], bfr[nt], acc[mt][nt], 0, 0, 0);
        }
        __syncthreads();
    }
    #pragma unroll
    for (int mt = 0; mt < 4; ++mt)
        #pragma unroll
        for (int nt = 0; nt < 2; ++nt)
            #pragma unroll
            for (int r = 0; r < 4; ++r) {
                const int row = bm + wm + mt * 16 + quad * 4 + r;
                const int cn = bn + wn + nt * 16 + col;
                Cf[(size_t)row * N + cn] = acc[mt][nt][r];
            }
}

// ---------------------------------------------------------------------------
// MFMA bf16 flash attention v10 (round-3 champion, VERBATIM).
// = v9 pipeline + select-skip. No setprio (round-4: -1.7%).
// ---------------------------------------------------------------------------
__global__ __launch_bounds__(512, 2) void flash_attn(
    const u16* __restrict__ qrw_b, const u16* __restrict__ qrr_b,
    const u16* __restrict__ kb, const u16* __restrict__ vbT,
    const u16* __restrict__ rkb, const int* __restrict__ mask,
    u16* __restrict__ ctxb)
{
    const int lane = threadIdx.x & 63;
    const int w    = threadIdx.x >> 6;      // 0..7
    const int quad = lane >> 4;
    const int col  = lane & 15;
    const int bh   = blockIdx.y;
    const int b    = bh >> 4;
    const int n    = bh & 15;
    const int B0   = blockIdx.x * 128;
    const int iw0  = B0 + w * 16;

    __shared__ u16 Ks[2][64 * 64];   // XOR-swizzled, double-buffered
    __shared__ u16 Vs[2][64 * 64];
    __shared__ u16 Rs[192 * 64];     // rk panel (circular, 3 x 64 rows)
    __shared__ u16 Pr[8][16][72];
    __shared__ u16 maddb[S_LEN];     // bf16 mask-add (0 or -16384)

    const size_t headQ = (size_t)bh * S_LEN * 64;
    const size_t headR = (size_t)n  * S_LEN * 64;

    for (int i = threadIdx.x; i < S_LEN; i += 512)
        maddb[i] = (u16)f2bs(mask[b * S_LEN + i] ? -16384.f : 0.f);

    bf16x8 a_rw[2], a_rr0[2], a_rr1[2];
    {
        const int r0 = iw0 + col;
        const int r1 = (r0 + 1 < S_LEN) ? (r0 + 1) : (S_LEN - 1);
        #pragma unroll
        for (int kc = 0; kc < 2; ++kc) {
            const int doff = kc * 32 + quad * 8;
            a_rw[kc]  = *(const bf16x8*)(qrw_b + headQ + (size_t)r0 * 64 + doff);
            a_rr0[kc] = *(const bf16x8*)(qrr_b + headQ + (size_t)r0 * 64 + doff);
            a_rr1[kc] = *(const bf16x8*)(qrr_b + headQ + (size_t)r1 * 64 + doff);
        }
    }

    f32x4 O[4];
    float l_acc[4] = {0.f, 0.f, 0.f, 0.f};
    #pragma unroll
    for (int dt = 0; dt < 4; ++dt) O[dt] = (f32x4){0.f, 0.f, 0.f, 0.f};

    const int swz  = ((lane & 7) ^ ((lane >> 3) & 7)) * 8;
    const int lrow = lane >> 3;
    const int csel = col & 7;

    // ---- prologue: stage step 0 (K, V chunk w; full 192-row R panel) ----
    {
        const int pbase0 = S_LEN - 128 - B0;        // dblk = B0 >= 0
        GL2LDS(kb + headQ + (size_t)(w * 8 + lrow) * 64 + swz, Ks[0] + w * 512);
        GL2LDS(vbT + ((size_t)bh * 64 + w * 8 + lrow) * S_LEN + swz, Vs[0] + w * 512);
        #pragma unroll
        for (int t = 0; t < 3; ++t) {
            const int c = w * 3 + t;                // 0..23
            int rr = pbase0 + c * 8 + lrow;
            rr = rr < 0 ? 0 : (rr > S_LEN - 1 ? S_LEN - 1 : rr);
            GL2LDS(rkb + headR + (size_t)rr * 64 + swz, Rs + c * 512);
        }
    }
    int roff = 0;
    __syncthreads();    // drains prologue vmcnt

    for (int u0 = 0; u0 < S_LEN; u0 += 64) {
        const int dblk = B0 - u0;                 // block-uniform, mult of 64
        const int dw = dblk + 16 * w;             // wave-uniform
        const bool mixed = (dw >= 0) && (dw <= 48);
        const int buf = (u0 >> 6) & 1;
        const int u1 = u0 + 64;
        const bool have_next = u1 < S_LEN;
        const bool next_full = (B0 - u1) == -64;  // region boundary ahead

        // mixed waves: direct-VGPR loads of the other region (issued FIRST so
        // their counted vmcnt wait doesn't drain the prefetches below)
        bf16x8 rf2[5][2];
        if (mixed) {
            #pragma unroll
            for (int g = 0; g < 5; ++g) {
                const int u = g * 16 + col;
                int row = (dblk >= 0) ? (u - dw - 17) : (S_LEN - 16 - dw + u);
                row = row < 0 ? 0 : (row > S_LEN - 1 ? S_LEN - 1 : row);
                const u16* rb = rkb + headR + (size_t)row * 64 + quad * 8;
                rf2[g][0] = *(const bf16x8*)(rb);
                rf2[g][1] = *(const bf16x8*)(rb + 32);
            }
        }

        // ---- prefetch next step: K/V -> alt LDS buffer, rk rows -> regs ----
        bf16x8 rpre;
        if (have_next) {
            GL2LDS(kb + headQ + (size_t)(u1 + w * 8 + lrow) * 64 + swz,
                   Ks[buf ^ 1] + w * 512);
            GL2LDS(vbT + ((size_t)bh * 64 + w * 8 + lrow) * S_LEN + u1 + swz,
                   Vs[buf ^ 1] + w * 512);
            if (!next_full) {
                const int dn = B0 - u1;
                const int pb = (dn >= 0) ? (S_LEN - 128 - dn) : (-dn - 129);
                int rr = pb + 128 + w * 8 + lrow;
                rr = rr < 0 ? 0 : (rr > S_LEN - 1 ? S_LEN - 1 : rr);
                rpre = *(const bf16x8*)(rkb + headR + (size_t)rr * 64 + swz);
            }
        }

        // ---- ac = Qrw . K^T ----
        f32x4 sc[4];
        #pragma unroll
        for (int nt = 0; nt < 4; ++nt) {
            const int m = nt * 16 + col;
            bf16x8 k0 = *(const bf16x8*)&Ks[buf][m * 64 + ((quad ^ csel) * 8)];
            bf16x8 k1 = *(const bf16x8*)&Ks[buf][m * 64 + (((4 + quad) ^ csel) * 8)];
            f32x4 c = (f32x4){0.f, 0.f, 0.f, 0.f};
            c = __builtin_amdgcn_mfma_f32_16x16x32_bf16(a_rw[0], k0, c, 0, 0, 0);
            c = __builtin_amdgcn_mfma_f32_16x16x32_bf16(a_rw[1], k1, c, 0, 0, 0);
            sc[nt] = c;
        }

        // ---- bd: panel GEMM ----
        f32x4 pnl[5];
        {
            const bf16x8* aP = (dblk >= 0) ? a_rr0 : a_rr1;
            #pragma unroll
            for (int g = 0; g < 5; ++g) {
                const int m = g * 16 + col + 112 - 16 * w;   // m&7 == col&7
                int slot = m + roff; if (slot >= 192) slot -= 192;
                bf16x8 r0 = *(const bf16x8*)&Rs[slot * 64 + ((quad ^ csel) * 8)];
                bf16x8 r1 = *(const bf16x8*)&Rs[slot * 64 + (((4 + quad) ^ csel) * 8)];
                f32x4 c = (f32x4){0.f, 0.f, 0.f, 0.f};
                c = __builtin_amdgcn_mfma_f32_16x16x32_bf16(aP[0], r0, c, 0, 0, 0);
                c = __builtin_amdgcn_mfma_f32_16x16x32_bf16(aP[1], r1, c, 0, 0, 0);
                pnl[g] = c;
            }
        }
        // ---- region stitch: only mixed waves and the dw==-16 wave differ
        //      from identity; wave-uniform branch. ----
        if (mixed || dw == -16) {
            f32x4 oth[5];
            #pragma unroll
            for (int g = 0; g < 5; ++g) oth[g] = (f32x4){0.f, 0.f, 0.f, 0.f};
            if (mixed) {
                const bf16x8* aV = (dblk >= 0) ? a_rr1 : a_rr0;
                #pragma unroll
                for (int g = 0; g < 5; ++g) {
                    f32x4 c = (f32x4){0.f, 0.f, 0.f, 0.f};
                    c = __builtin_amdgcn_mfma_f32_16x16x32_bf16(aV[0], rf2[g][0], c, 0, 0, 0);
                    c = __builtin_amdgcn_mfma_f32_16x16x32_bf16(aV[1], rf2[g][1], c, 0, 0, 0);
                    oth[g] = c;
                }
            }
            const int lim1 = 15 + dw;
            #pragma unroll
            for (int g = 0; g < 5; ++g) {
                const int u = g * 16 + col;
                #pragma unroll
                for (int r = 0; r < 4; ++r) {
                    const float r1v = (dblk >= 0) ? pnl[g][r] : oth[g][r];
                    const float r2v = (dblk >= 0) ? oth[g][r] : pnl[g][r];
                    pnl[g][r] = (u <= lim1) ? r1v : ((u == lim1 + 1) ? 0.f : r2v);
                }
            }
        }

        // ---- extract diagonal, add ac, scale, mask, exp, accumulate l ----
        #pragma unroll
        for (int nt = 0; nt < 4; ++nt) {
            const float ma = bs2f(maddb[u0 + nt * 16 + col]);
            #pragma unroll
            for (int r = 0; r < 4; ++r) {
                const int uo = col + 15 - quad * 4 - r;      // [0,30]
                const int src = (quad << 4) | (uo & 15);
                float blo = __shfl(pnl[nt][r], src, 64);
                float bhi = __shfl(pnl[nt + 1][r], src, 64);
                float bd = (uo < 16) ? blo : bhi;
                float p = __expf(fmaf(sc[nt][r] + bd, 0.125f, ma));
                sc[nt][r] = p;
                l_acc[r] += p;
            }
        }

        // ---- P: C-layout -> LDS row-major -> A-frags ----
        #pragma unroll
        for (int nt = 0; nt < 4; ++nt)
            #pragma unroll
            for (int r = 0; r < 4; ++r)
                Pr[w][quad * 4 + r][nt * 16 + col] = (u16)f2bs(sc[nt][r]);
        bf16x8 pa[2];
        pa[0] = *(const bf16x8*)&Pr[w][col][quad * 8];
        pa[1] = *(const bf16x8*)&Pr[w][col][32 + quad * 8];

        // ---- O += P . V ----
        #pragma unroll
        for (int dt = 0; dt < 4; ++dt) {
            const int m = dt * 16 + col;
            bf16x8 v0 = *(const bf16x8*)&Vs[buf][m * 64 + ((quad ^ csel) * 8)];
            bf16x8 v1 = *(const bf16x8*)&Vs[buf][m * 64 + (((4 + quad) ^ csel) * 8)];
            f32x4 c = O[dt];
            c = __builtin_amdgcn_mfma_f32_16x16x32_bf16(pa[0], v0, c, 0, 0, 0);
            c = __builtin_amdgcn_mfma_f32_16x16x32_bf16(pa[1], v1, c, 0, 0, 0);
            O[dt] = c;
        }

        // ---- publish next step's staging ----
        if (have_next) {
            __syncthreads();    // end of compute; K/V prefetch drains here (free)
            if (next_full) {
                // full R restage for the new region (pbase = -65), 3 chunks/wave
                #pragma unroll
                for (int t = 0; t < 3; ++t) {
                    const int c = w * 3 + t;
                    int rr = -65 + c * 8 + lrow;
                    rr = rr < 0 ? 0 : (rr > S_LEN - 1 ? S_LEN - 1 : rr);
                    GL2LDS(rkb + headR + (size_t)rr * 64 + swz, Rs + c * 512);
                }
                roff = 0;
            } else {
                // rolling: write the 8 prefetched rows into slots [roff, roff+64)
                *(bf16x8*)&Rs[((size_t)(roff + w * 8) << 6) + lane * 8] = rpre;
                roff += 64; if (roff >= 192) roff -= 192;
            }
            __syncthreads();    // publish Rs writes / drain boundary restage
        }
    }

    float inv[4];
    #pragma unroll
    for (int r = 0; r < 4; ++r) {
        float s = l_acc[r];
        #pragma unroll
        for (int off = 1; off < 16; off <<= 1)
            s += __shfl_xor(s, off, 64);
        inv[r] = 1.f / s;
    }
    #pragma unroll
    for (int dt = 0; dt < 4; ++dt)
        #pragma unroll
        for (int r = 0; r < 4; ++r) {
            const int i = iw0 + quad * 4 + r;
            ctxb[((size_t)b * S_LEN + i) * DMODEL + n * 64 + dt * 16 + col] =
                (u16)f2bs(O[dt][r] * inv[r]);
        }
}

// ---------------------------------------------------------------------------
// out = LayerNorm(x + attn_out)
// ---------------------------------------------------------------------------
__global__ __launch_bounds__(256) void ln_kernel(const float* __restrict__ x,
                                                 const float* __restrict__ ao,
                                                 const float* __restrict__ gamma,
                                                 const float* __restrict__ beta,
                                                 float* __restrict__ out) {
    const int r = blockIdx.x;
    const int tid = threadIdx.x;
    const size_t base = (size_t)r * DMODEL + tid * 4;
    float4 xv = *(const float4*)(x + base);
    float4 av = *(const float4*)(ao + base);
    float v0 = xv.x + av.x, v1 = xv.y + av.y, v2 = xv.z + av.z, v3 = xv.w + av.w;

    float s = v0 + v1 + v2 + v3;
    #pragma unroll
    for (int off = 32; off > 0; off >>= 1) s += __shfl_xor(s, off, 64);
    __shared__ float red[4];
    __shared__ float red2[4];
    if ((tid & 63) == 0) red[tid >> 6] = s;
    __syncthreads();
    float mu = (red[0] + red[1] + red[2] + red[3]) * (1.0f / DMODEL);

    float d0 = v0 - mu, d1 = v1 - mu, d2 = v2 - mu, d3 = v3 - mu;
    float q = d0 * d0 + d1 * d1 + d2 * d2 + d3 * d3;
    #pragma unroll
    for (int off = 32; off > 0; off >>= 1) q += __shfl_xor(q, off, 64);
    if ((tid & 63) == 0) red2[tid >> 6] = q;
    __syncthreads();
    float var = (red2[0] + red2[1] + red2[2] + red2[3]) * (1.0f / DMODEL);
    float rstd = rsqrtf(var + 1e-5f);

    float4 g  = *(const float4*)(gamma + tid * 4);
    float4 be = *(const float4*)(beta + tid * 4);
    float4 o = make_float4(d0 * rstd * g.x + be.x,
                           d1 * rstd * g.y + be.y,
                           d2 * rstd * g.z + be.z,
                           d3 * rstd * g.w + be.w);
    *(float4*)(out + base) = o;
}

// ---------------------------------------------------------------------------
extern "C" void kernel_launch(void* const* d_in, const int* in_sizes, int n_in,
                              void* d_out, int out_size, void* d_ws, size_t ws_size,
                              hipStream_t stream) {
    const float* x    = (const float*)d_in[0];
    const float* rpos = (const float*)d_in[1];
    const float* rwb  = (const float*)d_in[2];
    const float* rrb  = (const float*)d_in[3];
    const int*   mask = (const int*)  d_in[4];
    const float* Wqkv = (const float*)d_in[5];
    const float* Wrel = (const float*)d_in[6];
    const float* Wout = (const float*)d_in[7];
    const float* gam  = (const float*)d_in[8];
    const float* bet  = (const float*)d_in[9];
    float* out = (float*)d_out;

    // ---- workspace layout (u16 units), ~86 MB ----
    u16* wsb   = (u16*)d_ws;
    u16* ctxb  = wsb;                        // [4096][1024] bf16
    float* ao  = (float*)(wsb + 4194304);    // [4096][1024] f32
    u16* qrw_b = wsb + 12582912;             // [BH][S][64]
    u16* qrr_b = qrw_b + 4194304;
    u16* kb    = qrr_b + 4194304;
    u16* vbT   = kb + 4194304;               // [BH][64][S]
    u16* rkb   = vbT + 4194304;              // [NHEAD][S][64]
    u16* xb    = rkb + 2097152;              // [4096][1024]
    u16* rposb = xb + 4194304;               // [2048][1024]
    u16* Wqkvt = rposb + 2097152;            // [3072][1024]
    u16* Wrelt = Wqkvt + 3145728;            // [1024][1024]
    u16* Woutt = Wrelt + 1048576;            // [1024][1024]

    dim3 blk(256);
    prep_all<<<dim3(7424), blk, 0, stream>>>(x, rpos, Wqkv, Wrel, Wout,
                                             xb, rposb, Wqkvt, Wrelt, Woutt);
    gemm_qkv_rel<<<dim3(896), blk, 0, stream>>>(xb, Wqkvt, rposb, Wrelt,
                                                rwb, rrb,
                                                qrw_b, qrr_b, kb, vbT, rkb);
    flash_attn<<<dim3(S_LEN / 128, NBATCH * NHEAD), dim3(512), 0, stream>>>(
        qrw_b, qrr_b, kb, vbT, rkb, mask, ctxb);
    gemm_out<<<dim3(16, 32), blk, 0, stream>>>(ctxb, Woutt, ao, DMODEL, DMODEL);
    ln_kernel<<<dim3(NBATCH * S_LEN), blk, 0, stream>>>(x, ao, gam, bet, out);
}